// Round 1
// baseline (378.897 us; speedup 1.0000x reference)
//
#include <hip/hip_runtime.h>
#include <stdint.h>
#include <stddef.h>

#define DIMC 1024
#define LSEQ 2048
#define BSZ  4
#define DFFC 4096
#define NTOK (BSZ*LSEQ)   // 8192 tokens
#define NCHUNK 32
#define CHUNK 64          // NCHUNK*CHUNK == LSEQ

typedef __bf16 bf16x8 __attribute__((ext_vector_type(8)));
typedef float  f32x4  __attribute__((ext_vector_type(4)));

__device__ __forceinline__ unsigned short f2bf(float f) {
  unsigned int u = __float_as_uint(f);
  u += 0x7fffu + ((u >> 16) & 1u);      // RNE
  return (unsigned short)(u >> 16);
}

__device__ __forceinline__ void async16(const void* g, void* l) {
  __builtin_amdgcn_global_load_lds(
      (const __attribute__((address_space(1))) unsigned int*)(uintptr_t)g,
      (__attribute__((address_space(3))) unsigned int*)(uintptr_t)l,
      16, 0, 0);
}

// ---------------- LayerNorm stats: one block per token ----------------
__global__ __launch_bounds__(256) void ln_stats(const float* __restrict__ x,
                                                float* __restrict__ mu,
                                                float* __restrict__ rstd) {
  const int token = blockIdx.x;
  const float4* xp = (const float4*)(x + (size_t)token * DIMC);
  float4 v = xp[threadIdx.x];
  float s  = v.x + v.y + v.z + v.w;
  float s2 = v.x*v.x + v.y*v.y + v.z*v.z + v.w*v.w;
  #pragma unroll
  for (int o = 32; o; o >>= 1) { s += __shfl_down(s, o); s2 += __shfl_down(s2, o); }
  __shared__ float sh[8];
  const int lane = threadIdx.x & 63, w = threadIdx.x >> 6;
  if (lane == 0) { sh[w] = s; sh[4 + w] = s2; }
  __syncthreads();
  if (threadIdx.x == 0) {
    float ts  = sh[0] + sh[1] + sh[2] + sh[3];
    float ts2 = sh[4] + sh[5] + sh[6] + sh[7];
    float m = ts * (1.f / DIMC);
    float var = ts2 * (1.f / DIMC) - m * m;
    mu[token] = m;
    rstd[token] = rsqrtf(var + 1e-5f);
  }
}

// ---------------- LN apply -> bf16 (for GEMM A) ----------------
__global__ __launch_bounds__(256) void ln_apply_bf16(const float* __restrict__ x,
                                                     const float* __restrict__ mu,
                                                     const float* __restrict__ rstd,
                                                     const float* __restrict__ g,
                                                     const float* __restrict__ bb,
                                                     unsigned short* __restrict__ out) {
  const size_t i = (size_t)blockIdx.x * 256 + threadIdx.x;   // one float4 each
  float4 v = ((const float4*)x)[i];
  const int token = (int)(i >> 8);                 // (i*4)/1024
  const int d4 = (int)(i & 255);
  float4 gv = ((const float4*)g)[d4];
  float4 bv = ((const float4*)bb)[d4];
  const float m = mu[token], r = rstd[token];
  ushort4 o;
  o.x = f2bf((v.x - m) * r * gv.x + bv.x);
  o.y = f2bf((v.y - m) * r * gv.y + bv.y);
  o.z = f2bf((v.z - m) * r * gv.z + bv.z);
  o.w = f2bf((v.w - m) * r * gv.w + bv.w);
  ((ushort4*)out)[i] = o;
}

// ---------------- transpose fp32 [K][N] -> bf16 [N][K] ----------------
__global__ __launch_bounds__(256) void transpose_bf16(const float* __restrict__ w,
                                                      unsigned short* __restrict__ wt,
                                                      int K, int N) {
  __shared__ float tile[32][33];
  const int n0 = blockIdx.x * 32, k0 = blockIdx.y * 32;
  const int tx = threadIdx.x, ty = threadIdx.y;   // 32 x 8
  #pragma unroll
  for (int i = 0; i < 32; i += 8)
    tile[ty + i][tx] = w[(size_t)(k0 + ty + i) * N + n0 + tx];
  __syncthreads();
  #pragma unroll
  for (int i = 0; i < 32; i += 8)
    wt[(size_t)(n0 + ty + i) * K + k0 + tx] = f2bf(tile[tx][ty + i]);
}

// ---------------- spiral scan (3-phase chunked) ----------------
__device__ __forceinline__ void get_p(const float* __restrict__ phazor, int d,
                                      float& p_re, float& p_im) {
  float pre = phazor[2 * d], pim = phazor[2 * d + 1];
  float a = sqrtf(pre * pre + pim * pim);
  float sc = expf(-a) / a;
  p_re = pre * sc;
  p_im = pim * sc;
}

__global__ __launch_bounds__(256) void scan_phase1(const float* __restrict__ x,
                                                   const float* __restrict__ mu,
                                                   const float* __restrict__ rstd,
                                                   const float* __restrict__ g,
                                                   const float* __restrict__ bb,
                                                   const float* __restrict__ phazor,
                                                   float* __restrict__ Sre,
                                                   float* __restrict__ Sim) {
  const int d = blockIdx.x * 256 + threadIdx.x;
  const int c = blockIdx.y;
  const int b = blockIdx.z;
  float p_re, p_im; get_p(phazor, d, p_re, p_im);
  const float gd = g[d], bd = bb[d];
  const int t0 = c * CHUNK;
  const float* xp  = x + ((size_t)(b * LSEQ + t0)) * DIMC + d;
  const float* mup = mu + b * LSEQ + t0;
  const float* rp  = rstd + b * LSEQ + t0;
  float r_re = 0.f, r_im = 0.f;
  #pragma unroll 4
  for (int s = 0; s < CHUNK; ++s) {
    float hv = (xp[(size_t)s * DIMC] - mup[s]) * rp[s] * gd + bd;
    float nr = p_re * r_re - p_im * r_im + hv;
    float ni = p_re * r_im + p_im * r_re;
    r_re = nr; r_im = ni;
  }
  const int bd_i = b * DIMC + d;
  Sre[c * (BSZ * DIMC) + bd_i] = r_re;
  Sim[c * (BSZ * DIMC) + bd_i] = r_im;
}

__global__ __launch_bounds__(256) void scan_phase2(const float* __restrict__ phazor,
                                                   const float* __restrict__ Sre,
                                                   const float* __restrict__ Sim,
                                                   float* __restrict__ Cre,
                                                   float* __restrict__ Cim) {
  const int bd = blockIdx.x * 256 + threadIdx.x;  // 0..4095
  const int d = bd & (DIMC - 1);
  float p_re, p_im; get_p(phazor, d, p_re, p_im);
  float br = p_re, bi = p_im;                      // -> p^64
  #pragma unroll
  for (int i = 0; i < 6; ++i) { float t = br * br - bi * bi; bi = 2.f * br * bi; br = t; }
  float R_re = 0.f, R_im = 0.f;
  for (int c = 0; c < NCHUNK; ++c) {
    Cre[c * (BSZ * DIMC) + bd] = R_re;
    Cim[c * (BSZ * DIMC) + bd] = R_im;
    float sre = Sre[c * (BSZ * DIMC) + bd], sim = Sim[c * (BSZ * DIMC) + bd];
    float nr = br * R_re - bi * R_im + sre;
    float ni = br * R_im + bi * R_re + sim;
    R_re = nr; R_im = ni;
  }
}

__global__ __launch_bounds__(256) void scan_phase3(const float* __restrict__ x,
                                                   const float* __restrict__ mu,
                                                   const float* __restrict__ rstd,
                                                   const float* __restrict__ g,
                                                   const float* __restrict__ bb,
                                                   const float* __restrict__ phazor,
                                                   const float* __restrict__ phazor_init,
                                                   const float* __restrict__ last_re,
                                                   const float* __restrict__ last_im,
                                                   const float* __restrict__ Cre,
                                                   const float* __restrict__ Cim,
                                                   float* __restrict__ x2) {
  const int d = blockIdx.x * 256 + threadIdx.x;
  const int c = blockIdx.y;
  const int b = blockIdx.z;
  float p_re, p_im; get_p(phazor, d, p_re, p_im);
  const float pi_re = phazor_init[2 * d], pi_im = phazor_init[2 * d + 1];
  const float gd = g[d], bd_ = bb[d];
  const int bd_i = b * DIMC + d;
  float r_re = Cre[c * (BSZ * DIMC) + bd_i];
  float r_im = Cim[c * (BSZ * DIMC) + bd_i];
  // p^(64*c): square to p^64, then binary-exponentiate by c
  float br = p_re, bi = p_im;
  #pragma unroll
  for (int i = 0; i < 6; ++i) { float t = br * br - bi * bi; bi = 2.f * br * bi; br = t; }
  float er = 1.f, ei = 0.f;
  int e = c;
  while (e) {
    if (e & 1) { float t = er * br - ei * bi; ei = er * bi + ei * br; er = t; }
    float t2 = br * br - bi * bi; bi = 2.f * br * bi; br = t2;
    e >>= 1;
  }
  const float lre = last_re[bd_i], lim = last_im[bd_i];
  float q_re = lre * er - lim * ei;   // last * p^(64c)
  float q_im = lre * ei + lim * er;
  const int t0 = c * CHUNK;
  const float* xp  = x + ((size_t)(b * LSEQ + t0)) * DIMC + d;
  const float* mup = mu + b * LSEQ + t0;
  const float* rp  = rstd + b * LSEQ + t0;
  float* op = x2 + ((size_t)(b * LSEQ + t0)) * DIMC + d;
  #pragma unroll 4
  for (int s = 0; s < CHUNK; ++s) {
    float xv = xp[(size_t)s * DIMC];
    float hv = (xv - mup[s]) * rp[s] * gd + bd_;
    float nr = p_re * r_re - p_im * r_im + hv;
    float ni = p_re * r_im + p_im * r_re;
    r_re = nr; r_im = ni;
    float nq = p_re * q_re - p_im * q_im;       // q = last * p^(t+1)
    q_im = p_re * q_im + p_im * q_re;
    q_re = nq;
    op[(size_t)s * DIMC] = pi_re * r_re - pi_im * r_im + q_re + xv;
  }
}

// ---------------- bf16 MFMA GEMM, A [M][K], Bt [N][K] ----------------
// EPI 0: out = bf16( silu(acc + bias[n]) )          (hidden for GEMM2)
// EPI 1: out = f32 ( acc + bias[n] + resid[m][n] )  (final output)
template <int EPI>
__global__ __launch_bounds__(256) void gemm_bt(const unsigned short* __restrict__ A,
                                               const unsigned short* __restrict__ Bt,
                                               const float* __restrict__ bias,
                                               const float* __restrict__ resid,
                                               void* __restrict__ outp,
                                               int M, int N, int K) {
  __shared__ __align__(16) unsigned short As[128 * 64];
  __shared__ __align__(16) unsigned short Bs[128 * 64];
  const int tid = threadIdx.x;
  const int lane = tid & 63;
  const int bid = blockIdx.x;
  const int ntn = N >> 7;
  const int tm = (bid / ntn) << 7;
  const int tn = (bid % ntn) << 7;
  const int wave = tid >> 6;
  const int wm = (wave & 1) << 6;
  const int wn = (wave >> 1) << 6;

  f32x4 acc[4][4];
  #pragma unroll
  for (int i = 0; i < 4; ++i)
    #pragma unroll
    for (int j = 0; j < 4; ++j) acc[i][j] = (f32x4){0.f, 0.f, 0.f, 0.f};

  const int o0 = tid * 16;  // byte offset base in 16KB LDS tile
  for (int k0 = 0; k0 < K; k0 += 64) {
    #pragma unroll
    for (int c = 0; c < 4; ++c) {
      const int o = o0 + c * 4096;
      const int r = o >> 7;            // row (128B per row)
      const int ce = (o & 127) >> 1;   // bf16 col
      async16(A  + (size_t)(tm + r) * K + (k0 + ce), (char*)As + o);
      async16(Bt + (size_t)(tn + r) * K + (k0 + ce), (char*)Bs + o);
    }
    __syncthreads();   // drains vmcnt(0): LDS tiles ready
    #pragma unroll
    for (int kk = 0; kk < 2; ++kk) {
      bf16x8 av[4], bv[4];
      #pragma unroll
      for (int i = 0; i < 4; ++i)
        av[i] = *reinterpret_cast<const bf16x8*>(
            As + ((wm + i * 16 + (lane & 15)) << 6) + kk * 32 + ((lane >> 4) << 3));
      #pragma unroll
      for (int i = 0; i < 4; ++i)
        bv[i] = *reinterpret_cast<const bf16x8*>(
            Bs + ((wn + i * 16 + (lane & 15)) << 6) + kk * 32 + ((lane >> 4) << 3));
      #pragma unroll
      for (int mi = 0; mi < 4; ++mi)
        #pragma unroll
        for (int ni = 0; ni < 4; ++ni)
          acc[mi][ni] = __builtin_amdgcn_mfma_f32_16x16x32_bf16(av[mi], bv[ni], acc[mi][ni], 0, 0, 0);
    }
    __syncthreads();   // all waves done reading before next stage overwrites
  }

  // epilogue: C/D layout col = lane&15, row = (lane>>4)*4 + j  [HW-verified]
  const int rgrp = (lane >> 4) << 2;
  #pragma unroll
  for (int ni = 0; ni < 4; ++ni) {
    const int n = tn + wn + ni * 16 + (lane & 15);
    const float bv = bias[n];
    #pragma unroll
    for (int mi = 0; mi < 4; ++mi) {
      const int rb = tm + wm + mi * 16 + rgrp;
      #pragma unroll
      for (int j = 0; j < 4; ++j) {
        float v = acc[mi][ni][j] + bv;
        if constexpr (EPI == 0) {
          v = v / (1.f + __expf(-v));
          ((unsigned short*)outp)[(size_t)(rb + j) * N + n] = f2bf(v);
        } else {
          v += resid[(size_t)(rb + j) * N + n];
          ((float*)outp)[(size_t)(rb + j) * N + n] = v;
        }
      }
    }
  }
}

// ---------------- launch ----------------
extern "C" void kernel_launch(void* const* d_in, const int* in_sizes, int n_in,
                              void* d_out, int out_size, void* d_ws, size_t ws_size,
                              hipStream_t stream) {
  const float* x           = (const float*)d_in[0];
  const float* ln_g        = (const float*)d_in[1];
  const float* ln_b        = (const float*)d_in[2];
  const float* phazor      = (const float*)d_in[3];
  const float* phazor_init = (const float*)d_in[4];
  const float* w1          = (const float*)d_in[5];
  const float* b1          = (const float*)d_in[6];
  const float* w2          = (const float*)d_in[7];
  const float* b2          = (const float*)d_in[8];
  const float* last_re     = (const float*)d_in[9];
  const float* last_im     = (const float*)d_in[10];
  float* out = (float*)d_out;
  char* ws = (char*)d_ws;
  const size_t MB = 1ull << 20;

  float* x2  = (float*)(ws);                         // 32 MB
  float* mu1 = (float*)(ws + 32 * MB);               // 32 KB
  float* rs1 = (float*)(ws + 32 * MB + 64 * 1024);
  float* mu2 = (float*)(ws + 32 * MB + 128 * 1024);
  float* rs2 = (float*)(ws + 32 * MB + 192 * 1024);
  float* Sre = (float*)(ws + 32 * MB + 256 * 1024);  // 512 KB each
  float* Sim = (float*)(ws + 32 * MB + 768 * 1024);
  float* Cre = (float*)(ws + 32 * MB + 1280 * 1024);
  float* Cim = (float*)(ws + 32 * MB + 1792 * 1024);
  unsigned short* h2  = (unsigned short*)(ws + 35 * MB);   // 16 MB
  unsigned short* hid = (unsigned short*)(ws + 51 * MB);   // 64 MB
  unsigned short* w1t = (unsigned short*)(ws + 115 * MB);  // 8 MB
  unsigned short* w2t = (unsigned short*)(ws + 123 * MB);  // 8 MB (total 131 MB)

  transpose_bf16<<<dim3(DFFC / 32, DIMC / 32), dim3(32, 8), 0, stream>>>(w1, w1t, DIMC, DFFC);
  transpose_bf16<<<dim3(DIMC / 32, DFFC / 32), dim3(32, 8), 0, stream>>>(w2, w2t, DFFC, DIMC);

  ln_stats<<<NTOK, 256, 0, stream>>>(x, mu1, rs1);
  scan_phase1<<<dim3(DIMC / 256, NCHUNK, BSZ), 256, 0, stream>>>(x, mu1, rs1, ln_g, ln_b, phazor, Sre, Sim);
  scan_phase2<<<(BSZ * DIMC) / 256, 256, 0, stream>>>(phazor, Sre, Sim, Cre, Cim);
  scan_phase3<<<dim3(DIMC / 256, NCHUNK, BSZ), 256, 0, stream>>>(x, mu1, rs1, ln_g, ln_b, phazor,
                                                                 phazor_init, last_re, last_im,
                                                                 Cre, Cim, x2);
  ln_stats<<<NTOK, 256, 0, stream>>>(x2, mu2, rs2);
  ln_apply_bf16<<<NTOK, 256, 0, stream>>>(x2, mu2, rs2, ln_g, ln_b, h2);

  gemm_bt<0><<<(NTOK / 128) * (DFFC / 128), 256, 0, stream>>>(h2, w1t, b1, nullptr, hid, NTOK, DFFC, DIMC);
  gemm_bt<1><<<(NTOK / 128) * (DIMC / 128), 256, 0, stream>>>(hid, w2t, b2, x2, out, NTOK, DIMC, DFFC);
}

// Round 2
// 329.270 us; speedup vs baseline: 1.1507x; 1.1507x over previous
//
#include <hip/hip_runtime.h>
#include <stdint.h>
#include <stddef.h>

#define DIMC 1024
#define LSEQ 2048
#define BSZ  4
#define DFFC 4096
#define NTOK (BSZ*LSEQ)   // 8192 tokens
#define NCHUNK 32
#define CHUNK 64          // NCHUNK*CHUNK == LSEQ

typedef __bf16 bf16x8 __attribute__((ext_vector_type(8)));
typedef float  f32x4  __attribute__((ext_vector_type(4)));

__device__ __forceinline__ unsigned short f2bf(float f) {
  unsigned int u = __float_as_uint(f);
  u += 0x7fffu + ((u >> 16) & 1u);      // RNE
  return (unsigned short)(u >> 16);
}

__device__ __forceinline__ void async16(const void* g, void* l) {
  __builtin_amdgcn_global_load_lds(
      (const __attribute__((address_space(1))) unsigned int*)(uintptr_t)g,
      (__attribute__((address_space(3))) unsigned int*)(uintptr_t)l,
      16, 0, 0);
}

__device__ __forceinline__ void bar() {
  asm volatile("" ::: "memory");
  __builtin_amdgcn_s_barrier();
  asm volatile("" ::: "memory");
}
#define LGKM0 do { asm volatile("s_waitcnt lgkmcnt(0)" ::: "memory"); \
                   __builtin_amdgcn_sched_barrier(0); } while (0)
#define VMCNT(n) asm volatile("s_waitcnt vmcnt(" #n ")" ::: "memory")
#define MFMA_BF16 __builtin_amdgcn_mfma_f32_16x16x32_bf16

// ---------------- LayerNorm stats: one block per token ----------------
__global__ __launch_bounds__(256) void ln_stats(const float* __restrict__ x,
                                                float* __restrict__ mu,
                                                float* __restrict__ rstd) {
  const int token = blockIdx.x;
  const float4* xp = (const float4*)(x + (size_t)token * DIMC);
  float4 v = xp[threadIdx.x];
  float s  = v.x + v.y + v.z + v.w;
  float s2 = v.x*v.x + v.y*v.y + v.z*v.z + v.w*v.w;
  #pragma unroll
  for (int o = 32; o; o >>= 1) { s += __shfl_down(s, o); s2 += __shfl_down(s2, o); }
  __shared__ float sh[8];
  const int lane = threadIdx.x & 63, w = threadIdx.x >> 6;
  if (lane == 0) { sh[w] = s; sh[4 + w] = s2; }
  __syncthreads();
  if (threadIdx.x == 0) {
    float ts  = sh[0] + sh[1] + sh[2] + sh[3];
    float ts2 = sh[4] + sh[5] + sh[6] + sh[7];
    float m = ts * (1.f / DIMC);
    float var = ts2 * (1.f / DIMC) - m * m;
    mu[token] = m;
    rstd[token] = rsqrtf(var + 1e-5f);
  }
}

// ---------------- LN apply -> bf16 (for GEMM A) ----------------
__global__ __launch_bounds__(256) void ln_apply_bf16(const float* __restrict__ x,
                                                     const float* __restrict__ mu,
                                                     const float* __restrict__ rstd,
                                                     const float* __restrict__ g,
                                                     const float* __restrict__ bb,
                                                     unsigned short* __restrict__ out) {
  const size_t i = (size_t)blockIdx.x * 256 + threadIdx.x;   // one float4 each
  float4 v = ((const float4*)x)[i];
  const int token = (int)(i >> 8);
  const int d4 = (int)(i & 255);
  float4 gv = ((const float4*)g)[d4];
  float4 bv = ((const float4*)bb)[d4];
  const float m = mu[token], r = rstd[token];
  ushort4 o;
  o.x = f2bf((v.x - m) * r * gv.x + bv.x);
  o.y = f2bf((v.y - m) * r * gv.y + bv.y);
  o.z = f2bf((v.z - m) * r * gv.z + bv.z);
  o.w = f2bf((v.w - m) * r * gv.w + bv.w);
  ((ushort4*)out)[i] = o;
}

// ---------------- transpose fp32 [K][N] -> bf16 [N][K] ----------------
__global__ __launch_bounds__(256) void transpose_bf16(const float* __restrict__ w,
                                                      unsigned short* __restrict__ wt,
                                                      int K, int N) {
  __shared__ float tile[32][33];
  const int n0 = blockIdx.x * 32, k0 = blockIdx.y * 32;
  const int tx = threadIdx.x, ty = threadIdx.y;   // 32 x 8
  #pragma unroll
  for (int i = 0; i < 32; i += 8)
    tile[ty + i][tx] = w[(size_t)(k0 + ty + i) * N + n0 + tx];
  __syncthreads();
  #pragma unroll
  for (int i = 0; i < 32; i += 8)
    wt[(size_t)(n0 + ty + i) * K + k0 + tx] = f2bf(tile[tx][ty + i]);
}

// ---------------- spiral scan (3-phase chunked) ----------------
__device__ __forceinline__ void get_p(const float* __restrict__ phazor, int d,
                                      float& p_re, float& p_im) {
  float pre = phazor[2 * d], pim = phazor[2 * d + 1];
  float a = sqrtf(pre * pre + pim * pim);
  float sc = expf(-a) / a;
  p_re = pre * sc;
  p_im = pim * sc;
}

__global__ __launch_bounds__(256) void scan_phase1(const float* __restrict__ x,
                                                   const float* __restrict__ mu,
                                                   const float* __restrict__ rstd,
                                                   const float* __restrict__ g,
                                                   const float* __restrict__ bb,
                                                   const float* __restrict__ phazor,
                                                   float* __restrict__ Sre,
                                                   float* __restrict__ Sim) {
  const int d = blockIdx.x * 256 + threadIdx.x;
  const int c = blockIdx.y;
  const int b = blockIdx.z;
  float p_re, p_im; get_p(phazor, d, p_re, p_im);
  const float gd = g[d], bd = bb[d];
  const int t0 = c * CHUNK;
  const float* xp  = x + ((size_t)(b * LSEQ + t0)) * DIMC + d;
  const float* mup = mu + b * LSEQ + t0;
  const float* rp  = rstd + b * LSEQ + t0;
  float r_re = 0.f, r_im = 0.f;
  #pragma unroll 4
  for (int s = 0; s < CHUNK; ++s) {
    float hv = (xp[(size_t)s * DIMC] - mup[s]) * rp[s] * gd + bd;
    float nr = p_re * r_re - p_im * r_im + hv;
    float ni = p_re * r_im + p_im * r_re;
    r_re = nr; r_im = ni;
  }
  const int bd_i = b * DIMC + d;
  Sre[c * (BSZ * DIMC) + bd_i] = r_re;
  Sim[c * (BSZ * DIMC) + bd_i] = r_im;
}

__global__ __launch_bounds__(256) void scan_phase2(const float* __restrict__ phazor,
                                                   const float* __restrict__ Sre,
                                                   const float* __restrict__ Sim,
                                                   float* __restrict__ Cre,
                                                   float* __restrict__ Cim) {
  const int bd = blockIdx.x * 256 + threadIdx.x;  // 0..4095
  const int d = bd & (DIMC - 1);
  float p_re, p_im; get_p(phazor, d, p_re, p_im);
  float br = p_re, bi = p_im;                      // -> p^64
  #pragma unroll
  for (int i = 0; i < 6; ++i) { float t = br * br - bi * bi; bi = 2.f * br * bi; br = t; }
  float R_re = 0.f, R_im = 0.f;
  for (int c = 0; c < NCHUNK; ++c) {
    Cre[c * (BSZ * DIMC) + bd] = R_re;
    Cim[c * (BSZ * DIMC) + bd] = R_im;
    float sre = Sre[c * (BSZ * DIMC) + bd], sim = Sim[c * (BSZ * DIMC) + bd];
    float nr = br * R_re - bi * R_im + sre;
    float ni = br * R_im + bi * R_re + sim;
    R_re = nr; R_im = ni;
  }
}

__global__ __launch_bounds__(256) void scan_phase3(const float* __restrict__ x,
                                                   const float* __restrict__ mu,
                                                   const float* __restrict__ rstd,
                                                   const float* __restrict__ g,
                                                   const float* __restrict__ bb,
                                                   const float* __restrict__ phazor,
                                                   const float* __restrict__ phazor_init,
                                                   const float* __restrict__ last_re,
                                                   const float* __restrict__ last_im,
                                                   const float* __restrict__ Cre,
                                                   const float* __restrict__ Cim,
                                                   float* __restrict__ x2) {
  const int d = blockIdx.x * 256 + threadIdx.x;
  const int c = blockIdx.y;
  const int b = blockIdx.z;
  float p_re, p_im; get_p(phazor, d, p_re, p_im);
  const float pi_re = phazor_init[2 * d], pi_im = phazor_init[2 * d + 1];
  const float gd = g[d], bd_ = bb[d];
  const int bd_i = b * DIMC + d;
  float r_re = Cre[c * (BSZ * DIMC) + bd_i];
  float r_im = Cim[c * (BSZ * DIMC) + bd_i];
  float br = p_re, bi = p_im;
  #pragma unroll
  for (int i = 0; i < 6; ++i) { float t = br * br - bi * bi; bi = 2.f * br * bi; br = t; }
  float er = 1.f, ei = 0.f;
  int e = c;
  while (e) {
    if (e & 1) { float t = er * br - ei * bi; ei = er * bi + ei * br; er = t; }
    float t2 = br * br - bi * bi; bi = 2.f * br * bi; br = t2;
    e >>= 1;
  }
  const float lre = last_re[bd_i], lim = last_im[bd_i];
  float q_re = lre * er - lim * ei;
  float q_im = lre * ei + lim * er;
  const int t0 = c * CHUNK;
  const float* xp  = x + ((size_t)(b * LSEQ + t0)) * DIMC + d;
  const float* mup = mu + b * LSEQ + t0;
  const float* rp  = rstd + b * LSEQ + t0;
  float* op = x2 + ((size_t)(b * LSEQ + t0)) * DIMC + d;
  #pragma unroll 4
  for (int s = 0; s < CHUNK; ++s) {
    float xv = xp[(size_t)s * DIMC];
    float hv = (xv - mup[s]) * rp[s] * gd + bd_;
    float nr = p_re * r_re - p_im * r_im + hv;
    float ni = p_re * r_im + p_im * r_re;
    r_re = nr; r_im = ni;
    float nq = p_re * q_re - p_im * q_im;
    q_im = p_re * q_im + p_im * q_re;
    q_re = nq;
    op[(size_t)s * DIMC] = pi_re * r_re - pi_im * r_im + q_re + xv;
  }
}

// ---------------- 8-phase-style pipelined MFMA GEMM ----------------
// A [M][K] bf16, Bt [N][K] bf16. BM=256 fixed, BN template (256 or 128).
// 512 threads, 8 waves as 2(M) x 4(N). K-tile = 64, split in two kk-halves
// of 32 cols. LDS blocks per buffer: A_kk0, A_kk1, B_kk0, B_kk1, each
// [rows][32 bf16] with 16B-group XOR swizzle  c' = c ^ ((row>>1)&3)
// (both-sides: pre-swizzled global source + swizzled ds_read).
// Counted vmcnt keeps 3-4 staging loads in flight across every barrier.
// EPI 0: out = bf16(silu(acc+bias))   EPI 1: out = f32(acc+bias+resid)
template<int BN, int EPI>
__global__ __launch_bounds__(512, 2) void gemm8(const unsigned short* __restrict__ A,
                                                const unsigned short* __restrict__ Bt,
                                                const float* __restrict__ bias,
                                                const float* __restrict__ resid,
                                                void* __restrict__ outp,
                                                int M, int N, int K) {
  constexpr int AUS = 256 * 32;          // ushorts per A kk-block (16 KB)
  constexpr int BUS = BN * 32;           // ushorts per B kk-block
  constexpr int BUFUS = 2 * AUS + 2 * BUS;
  constexpr int NI = BN / 64;            // ni per wave (4 or 2)
  __shared__ __align__(16) unsigned short lds[2 * BUFUS];

  const int tid  = threadIdx.x;
  const int lane = tid & 63;
  const int wave = tid >> 6;
  const int wm = (wave & 1) * 128;
  const int wn = (wave >> 1) * (BN / 4);
  const int r15 = lane & 15;
  const int cus = ((lane >> 4) ^ ((r15 >> 1) & 3)) * 8;  // swizzled col (ushorts)

  int bid = blockIdx.x;                   // XCD-aware swizzle (grid % 8 == 0)
  const int cpx = gridDim.x >> 3;
  bid = (bid & 7) * cpx + (bid >> 3);
  const int ntn = N / BN;
  const int tm = (bid / ntn) * 256;
  const int tn = (bid % ntn) * BN;
  const int NT = K >> 6;

  f32x4 acc[8][NI];
  #pragma unroll
  for (int i = 0; i < 8; ++i)
    #pragma unroll
    for (int j = 0; j < NI; ++j) acc[i][j] = (f32x4){0.f, 0.f, 0.f, 0.f};

  auto stageA = [&](int buf, int kk, int k0) {
    unsigned short* blk = lds + buf * BUFUS + kk * AUS;
    const unsigned short* g = A + (size_t)tm * K + k0 + kk * 32;
    #pragma unroll
    for (int r = 0; r < 2; ++r) {
      const int s = r * 512 + tid;
      const int row = s >> 2;
      const int cg = (s & 3) ^ ((s >> 3) & 3);   // inverse (=same) swizzle on source
      async16(g + (size_t)row * K + cg * 8, blk + (size_t)s * 8);
    }
  };
  auto stageB = [&](int buf, int kk, int k0) {
    unsigned short* blk = lds + buf * BUFUS + 2 * AUS + kk * BUS;
    const unsigned short* g = Bt + (size_t)tn * K + k0 + kk * 32;
    #pragma unroll
    for (int r = 0; r < BN / 128; ++r) {
      const int s = r * 512 + tid;
      const int row = s >> 2;
      const int cg = (s & 3) ^ ((s >> 3) & 3);
      async16(g + (size_t)row * K + cg * 8, blk + (size_t)s * 8);
    }
  };
  auto rdA = [&](int buf, int kk, int mi) -> bf16x8 {
    return *(const bf16x8*)(lds + buf * BUFUS + kk * AUS + (wm + mi * 16 + r15) * 32 + cus);
  };
  auto rdB = [&](int buf, int kk, int ni) -> bf16x8 {
    return *(const bf16x8*)(lds + buf * BUFUS + 2 * AUS + kk * BUS + (wn + ni * 16 + r15) * 32 + cus);
  };

  bf16x8 af[8], bq0, bq1;

  // prologue: tile 0 fully staged; vmcnt(4|3) leaves kk1 loads in flight
  stageA(0, 0, 0); stageB(0, 0, 0); stageA(0, 1, 0); stageB(0, 1, 0);
  if constexpr (BN == 256) VMCNT(4); else VMCNT(3);
  bar();

  for (int t = 0; t < NT - 1; ++t) {
    const int buf = t & 1, nb = buf ^ 1, kn = (t + 1) << 6;
    if constexpr (BN == 256) {
      // P0: kk0, ni 0-1
      #pragma unroll
      for (int mi = 0; mi < 8; ++mi) af[mi] = rdA(buf, 0, mi);
      bq0 = rdB(buf, 0, 0); bq1 = rdB(buf, 0, 1);
      stageA(nb, 0, kn);
      bar(); LGKM0;
      __builtin_amdgcn_s_setprio(1);
      #pragma unroll
      for (int mi = 0; mi < 8; ++mi) {
        acc[mi][0] = MFMA_BF16(af[mi], bq0, acc[mi][0], 0, 0, 0);
        acc[mi][1] = MFMA_BF16(af[mi], bq1, acc[mi][1], 0, 0, 0);
      }
      __builtin_amdgcn_s_setprio(0);
      bar();
      // P1: kk0, ni 2-3
      bq0 = rdB(buf, 0, 2); bq1 = rdB(buf, 0, 3);
      stageB(nb, 0, kn);
      bar(); LGKM0;
      __builtin_amdgcn_s_setprio(1);
      #pragma unroll
      for (int mi = 0; mi < 8; ++mi) {
        acc[mi][2] = MFMA_BF16(af[mi], bq0, acc[mi][2], 0, 0, 0);
        acc[mi][3] = MFMA_BF16(af[mi], bq1, acc[mi][3], 0, 0, 0);
      }
      __builtin_amdgcn_s_setprio(0);
      VMCNT(4);      // kk1(t) landed; kk0(t+1) still in flight
      bar();
      // P2: kk1, ni 0-1
      #pragma unroll
      for (int mi = 0; mi < 8; ++mi) af[mi] = rdA(buf, 1, mi);
      bq0 = rdB(buf, 1, 0); bq1 = rdB(buf, 1, 1);
      stageA(nb, 1, kn);
      bar(); LGKM0;
      __builtin_amdgcn_s_setprio(1);
      #pragma unroll
      for (int mi = 0; mi < 8; ++mi) {
        acc[mi][0] = MFMA_BF16(af[mi], bq0, acc[mi][0], 0, 0, 0);
        acc[mi][1] = MFMA_BF16(af[mi], bq1, acc[mi][1], 0, 0, 0);
      }
      __builtin_amdgcn_s_setprio(0);
      bar();
      // P3: kk1, ni 2-3
      bq0 = rdB(buf, 1, 2); bq1 = rdB(buf, 1, 3);
      stageB(nb, 1, kn);
      bar(); LGKM0;
      __builtin_amdgcn_s_setprio(1);
      #pragma unroll
      for (int mi = 0; mi < 8; ++mi) {
        acc[mi][2] = MFMA_BF16(af[mi], bq0, acc[mi][2], 0, 0, 0);
        acc[mi][3] = MFMA_BF16(af[mi], bq1, acc[mi][3], 0, 0, 0);
      }
      __builtin_amdgcn_s_setprio(0);
      VMCNT(4);      // kk0(t+1) landed; kk1(t+1) still in flight
      bar();
    } else {
      // P0: kk0, both ni
      #pragma unroll
      for (int mi = 0; mi < 8; ++mi) af[mi] = rdA(buf, 0, mi);
      bq0 = rdB(buf, 0, 0); bq1 = rdB(buf, 0, 1);
      stageA(nb, 0, kn); stageB(nb, 0, kn);
      bar(); LGKM0;
      __builtin_amdgcn_s_setprio(1);
      #pragma unroll
      for (int mi = 0; mi < 8; ++mi) {
        acc[mi][0] = MFMA_BF16(af[mi], bq0, acc[mi][0], 0, 0, 0);
        acc[mi][1] = MFMA_BF16(af[mi], bq1, acc[mi][1], 0, 0, 0);
      }
      __builtin_amdgcn_s_setprio(0);
      VMCNT(3);
      bar();
      // P1: kk1, both ni
      #pragma unroll
      for (int mi = 0; mi < 8; ++mi) af[mi] = rdA(buf, 1, mi);
      bq0 = rdB(buf, 1, 0); bq1 = rdB(buf, 1, 1);
      stageA(nb, 1, kn); stageB(nb, 1, kn);
      bar(); LGKM0;
      __builtin_amdgcn_s_setprio(1);
      #pragma unroll
      for (int mi = 0; mi < 8; ++mi) {
        acc[mi][0] = MFMA_BF16(af[mi], bq0, acc[mi][0], 0, 0, 0);
        acc[mi][1] = MFMA_BF16(af[mi], bq1, acc[mi][1], 0, 0, 0);
      }
      __builtin_amdgcn_s_setprio(0);
      VMCNT(3);
      bar();
    }
  }

  // final iteration (no staging)
  {
    const int buf = (NT - 1) & 1;
    if constexpr (BN == 256) {
      #pragma unroll
      for (int mi = 0; mi < 8; ++mi) af[mi] = rdA(buf, 0, mi);
      bq0 = rdB(buf, 0, 0); bq1 = rdB(buf, 0, 1);
      bar(); LGKM0;
      #pragma unroll
      for (int mi = 0; mi < 8; ++mi) {
        acc[mi][0] = MFMA_BF16(af[mi], bq0, acc[mi][0], 0, 0, 0);
        acc[mi][1] = MFMA_BF16(af[mi], bq1, acc[mi][1], 0, 0, 0);
      }
      bar();
      bq0 = rdB(buf, 0, 2); bq1 = rdB(buf, 0, 3);
      bar(); LGKM0;
      #pragma unroll
      for (int mi = 0; mi < 8; ++mi) {
        acc[mi][2] = MFMA_BF16(af[mi], bq0, acc[mi][2], 0, 0, 0);
        acc[mi][3] = MFMA_BF16(af[mi], bq1, acc[mi][3], 0, 0, 0);
      }
      VMCNT(0);      // kk1 of final tile
      bar();
      #pragma unroll
      for (int mi = 0; mi < 8; ++mi) af[mi] = rdA(buf, 1, mi);
      bq0 = rdB(buf, 1, 0); bq1 = rdB(buf, 1, 1);
      bar(); LGKM0;
      #pragma unroll
      for (int mi = 0; mi < 8; ++mi) {
        acc[mi][0] = MFMA_BF16(af[mi], bq0, acc[mi][0], 0, 0, 0);
        acc[mi][1] = MFMA_BF16(af[mi], bq1, acc[mi][1], 0, 0, 0);
      }
      bar();
      bq0 = rdB(buf, 1, 2); bq1 = rdB(buf, 1, 3);
      LGKM0;
      #pragma unroll
      for (int mi = 0; mi < 8; ++mi) {
        acc[mi][2] = MFMA_BF16(af[mi], bq0, acc[mi][2], 0, 0, 0);
        acc[mi][3] = MFMA_BF16(af[mi], bq1, acc[mi][3], 0, 0, 0);
      }
    } else {
      #pragma unroll
      for (int mi = 0; mi < 8; ++mi) af[mi] = rdA(buf, 0, mi);
      bq0 = rdB(buf, 0, 0); bq1 = rdB(buf, 0, 1);
      bar(); LGKM0;
      #pragma unroll
      for (int mi = 0; mi < 8; ++mi) {
        acc[mi][0] = MFMA_BF16(af[mi], bq0, acc[mi][0], 0, 0, 0);
        acc[mi][1] = MFMA_BF16(af[mi], bq1, acc[mi][1], 0, 0, 0);
      }
      VMCNT(0);
      bar();
      #pragma unroll
      for (int mi = 0; mi < 8; ++mi) af[mi] = rdA(buf, 1, mi);
      bq0 = rdB(buf, 1, 0); bq1 = rdB(buf, 1, 1);
      LGKM0;
      #pragma unroll
      for (int mi = 0; mi < 8; ++mi) {
        acc[mi][0] = MFMA_BF16(af[mi], bq0, acc[mi][0], 0, 0, 0);
        acc[mi][1] = MFMA_BF16(af[mi], bq1, acc[mi][1], 0, 0, 0);
      }
    }
  }

  // epilogue: C/D layout col = lane&15, row = (lane>>4)*4 + j
  const int rg = (lane >> 4) * 4;
  #pragma unroll
  for (int ni = 0; ni < NI; ++ni) {
    const int n = tn + wn + ni * 16 + r15;
    const float bv = bias[n];
    #pragma unroll
    for (int mi = 0; mi < 8; ++mi) {
      const int rb = tm + wm + mi * 16 + rg;
      #pragma unroll
      for (int j = 0; j < 4; ++j) {
        float v = acc[mi][ni][j] + bv;
        if constexpr (EPI == 0) {
          v = v / (1.f + __expf(-v));
          ((unsigned short*)outp)[(size_t)(rb + j) * N + n] = f2bf(v);
        } else {
          v += resid[(size_t)(rb + j) * N + n];
          ((float*)outp)[(size_t)(rb + j) * N + n] = v;
        }
      }
    }
  }
}

// ---------------- launch ----------------
extern "C" void kernel_launch(void* const* d_in, const int* in_sizes, int n_in,
                              void* d_out, int out_size, void* d_ws, size_t ws_size,
                              hipStream_t stream) {
  const float* x           = (const float*)d_in[0];
  const float* ln_g        = (const float*)d_in[1];
  const float* ln_b        = (const float*)d_in[2];
  const float* phazor      = (const float*)d_in[3];
  const float* phazor_init = (const float*)d_in[4];
  const float* w1          = (const float*)d_in[5];
  const float* b1          = (const float*)d_in[6];
  const float* w2          = (const float*)d_in[7];
  const float* b2          = (const float*)d_in[8];
  const float* last_re     = (const float*)d_in[9];
  const float* last_im     = (const float*)d_in[10];
  float* out = (float*)d_out;
  char* ws = (char*)d_ws;
  const size_t MB = 1ull << 20;

  float* x2  = (float*)(ws);                         // 32 MB
  float* mu1 = (float*)(ws + 32 * MB);               // 32 KB
  float* rs1 = (float*)(ws + 32 * MB + 64 * 1024);
  float* mu2 = (float*)(ws + 32 * MB + 128 * 1024);
  float* rs2 = (float*)(ws + 32 * MB + 192 * 1024);
  float* Sre = (float*)(ws + 32 * MB + 256 * 1024);  // 512 KB each
  float* Sim = (float*)(ws + 32 * MB + 768 * 1024);
  float* Cre = (float*)(ws + 32 * MB + 1280 * 1024);
  float* Cim = (float*)(ws + 32 * MB + 1792 * 1024);
  unsigned short* h2  = (unsigned short*)(ws + 35 * MB);   // 16 MB
  unsigned short* hid = (unsigned short*)(ws + 51 * MB);   // 64 MB
  unsigned short* w1t = (unsigned short*)(ws + 115 * MB);  // 8 MB
  unsigned short* w2t = (unsigned short*)(ws + 123 * MB);  // 8 MB

  transpose_bf16<<<dim3(DFFC / 32, DIMC / 32), dim3(32, 8), 0, stream>>>(w1, w1t, DIMC, DFFC);
  transpose_bf16<<<dim3(DIMC / 32, DFFC / 32), dim3(32, 8), 0, stream>>>(w2, w2t, DFFC, DIMC);

  ln_stats<<<NTOK, 256, 0, stream>>>(x, mu1, rs1);
  scan_phase1<<<dim3(DIMC / 256, NCHUNK, BSZ), 256, 0, stream>>>(x, mu1, rs1, ln_g, ln_b, phazor, Sre, Sim);
  scan_phase2<<<(BSZ * DIMC) / 256, 256, 0, stream>>>(phazor, Sre, Sim, Cre, Cim);
  scan_phase3<<<dim3(DIMC / 256, NCHUNK, BSZ), 256, 0, stream>>>(x, mu1, rs1, ln_g, ln_b, phazor,
                                                                 phazor_init, last_re, last_im,
                                                                 Cre, Cim, x2);
  ln_stats<<<NTOK, 256, 0, stream>>>(x2, mu2, rs2);
  ln_apply_bf16<<<NTOK, 256, 0, stream>>>(x2, mu2, rs2, ln_g, ln_b, h2);

  gemm8<256, 0><<<(NTOK / 256) * (DFFC / 256), 512, 0, stream>>>(h2, w1t, b1, nullptr, hid,
                                                                 NTOK, DFFC, DIMC);
  gemm8<128, 1><<<(NTOK / 256) * (DIMC / 128), 512, 0, stream>>>(hid, w2t, b2, x2, out,
                                                                 NTOK, DIMC, DFFC);
}

// Round 3
// 329.114 us; speedup vs baseline: 1.1513x; 1.0005x over previous
//
#include <hip/hip_runtime.h>
#include <stdint.h>
#include <stddef.h>

#define DIMC 1024
#define LSEQ 2048
#define BSZ  4
#define DFFC 4096
#define NTOK (BSZ*LSEQ)   // 8192 tokens
#define NCHUNK 32
#define CHUNK 64          // NCHUNK*CHUNK == LSEQ

typedef __bf16 bf16x8 __attribute__((ext_vector_type(8)));
typedef float  f32x4  __attribute__((ext_vector_type(4)));

__device__ __forceinline__ unsigned short f2bf(float f) {
  unsigned int u = __float_as_uint(f);
  u += 0x7fffu + ((u >> 16) & 1u);      // RNE
  return (unsigned short)(u >> 16);
}

__device__ __forceinline__ void async16(const void* g, void* l) {
  __builtin_amdgcn_global_load_lds(
      (const __attribute__((address_space(1))) unsigned int*)(uintptr_t)g,
      (__attribute__((address_space(3))) unsigned int*)(uintptr_t)l,
      16, 0, 0);
}

__device__ __forceinline__ void bar() {
  asm volatile("" ::: "memory");
  __builtin_amdgcn_s_barrier();
  asm volatile("" ::: "memory");
}
#define VMCNT(n) asm volatile("s_waitcnt vmcnt(" #n ")" ::: "memory")
#define MFMA_BF16 __builtin_amdgcn_mfma_f32_16x16x32_bf16

// ---------------- LayerNorm stats: one block per token ----------------
__global__ __launch_bounds__(256) void ln_stats(const float* __restrict__ x,
                                                float* __restrict__ mu,
                                                float* __restrict__ rstd) {
  const int token = blockIdx.x;
  const float4* xp = (const float4*)(x + (size_t)token * DIMC);
  float4 v = xp[threadIdx.x];
  float s  = v.x + v.y + v.z + v.w;
  float s2 = v.x*v.x + v.y*v.y + v.z*v.z + v.w*v.w;
  #pragma unroll
  for (int o = 32; o; o >>= 1) { s += __shfl_down(s, o); s2 += __shfl_down(s2, o); }
  __shared__ float sh[8];
  const int lane = threadIdx.x & 63, w = threadIdx.x >> 6;
  if (lane == 0) { sh[w] = s; sh[4 + w] = s2; }
  __syncthreads();
  if (threadIdx.x == 0) {
    float ts  = sh[0] + sh[1] + sh[2] + sh[3];
    float ts2 = sh[4] + sh[5] + sh[6] + sh[7];
    float m = ts * (1.f / DIMC);
    float var = ts2 * (1.f / DIMC) - m * m;
    mu[token] = m;
    rstd[token] = rsqrtf(var + 1e-5f);
  }
}

// ---------------- fused LN (stats + apply) -> bf16 ----------------
__global__ __launch_bounds__(256) void ln_fused_bf16(const float* __restrict__ x,
                                                     const float* __restrict__ g,
                                                     const float* __restrict__ bb,
                                                     unsigned short* __restrict__ out) {
  const int token = blockIdx.x;
  const float4* xp = (const float4*)(x + (size_t)token * DIMC);
  float4 v = xp[threadIdx.x];
  float s  = v.x + v.y + v.z + v.w;
  float s2 = v.x*v.x + v.y*v.y + v.z*v.z + v.w*v.w;
  #pragma unroll
  for (int o = 32; o; o >>= 1) { s += __shfl_down(s, o); s2 += __shfl_down(s2, o); }
  __shared__ float sh[10];
  const int lane = threadIdx.x & 63, w = threadIdx.x >> 6;
  if (lane == 0) { sh[w] = s; sh[4 + w] = s2; }
  __syncthreads();
  if (threadIdx.x == 0) {
    float ts  = sh[0] + sh[1] + sh[2] + sh[3];
    float ts2 = sh[4] + sh[5] + sh[6] + sh[7];
    float m = ts * (1.f / DIMC);
    float var = ts2 * (1.f / DIMC) - m * m;
    sh[8] = m;
    sh[9] = rsqrtf(var + 1e-5f);
  }
  __syncthreads();
  const float m = sh[8], r = sh[9];
  float4 gv = ((const float4*)g)[threadIdx.x];
  float4 bv = ((const float4*)bb)[threadIdx.x];
  ushort4 o;
  o.x = f2bf((v.x - m) * r * gv.x + bv.x);
  o.y = f2bf((v.y - m) * r * gv.y + bv.y);
  o.z = f2bf((v.z - m) * r * gv.z + bv.z);
  o.w = f2bf((v.w - m) * r * gv.w + bv.w);
  ((ushort4*)(out + (size_t)token * DIMC))[threadIdx.x] = o;
}

// ---------------- transpose fp32 [K][N] -> bf16 [N][K] ----------------
__global__ __launch_bounds__(256) void transpose_bf16(const float* __restrict__ w,
                                                      unsigned short* __restrict__ wt,
                                                      int K, int N) {
  __shared__ float tile[32][33];
  const int n0 = blockIdx.x * 32, k0 = blockIdx.y * 32;
  const int tx = threadIdx.x, ty = threadIdx.y;   // 32 x 8
  #pragma unroll
  for (int i = 0; i < 32; i += 8)
    tile[ty + i][tx] = w[(size_t)(k0 + ty + i) * N + n0 + tx];
  __syncthreads();
  #pragma unroll
  for (int i = 0; i < 32; i += 8)
    wt[(size_t)(n0 + ty + i) * K + k0 + tx] = f2bf(tile[tx][ty + i]);
}

// ---------------- spiral scan (3-phase chunked) ----------------
__device__ __forceinline__ void get_p(const float* __restrict__ phazor, int d,
                                      float& p_re, float& p_im) {
  float pre = phazor[2 * d], pim = phazor[2 * d + 1];
  float a = sqrtf(pre * pre + pim * pim);
  float sc = expf(-a) / a;
  p_re = pre * sc;
  p_im = pim * sc;
}

__global__ __launch_bounds__(256) void scan_phase1(const float* __restrict__ x,
                                                   const float* __restrict__ mu,
                                                   const float* __restrict__ rstd,
                                                   const float* __restrict__ g,
                                                   const float* __restrict__ bb,
                                                   const float* __restrict__ phazor,
                                                   float* __restrict__ Sre,
                                                   float* __restrict__ Sim) {
  const int d = blockIdx.x * 256 + threadIdx.x;
  const int c = blockIdx.y;
  const int b = blockIdx.z;
  float p_re, p_im; get_p(phazor, d, p_re, p_im);
  const float gd = g[d], bd = bb[d];
  const int t0 = c * CHUNK;
  const float* xp  = x + ((size_t)(b * LSEQ + t0)) * DIMC + d;
  const float* mup = mu + b * LSEQ + t0;
  const float* rp  = rstd + b * LSEQ + t0;
  float r_re = 0.f, r_im = 0.f;
  #pragma unroll 4
  for (int s = 0; s < CHUNK; ++s) {
    float hv = (xp[(size_t)s * DIMC] - mup[s]) * rp[s] * gd + bd;
    float nr = p_re * r_re - p_im * r_im + hv;
    float ni = p_re * r_im + p_im * r_re;
    r_re = nr; r_im = ni;
  }
  const int bd_i = b * DIMC + d;
  Sre[c * (BSZ * DIMC) + bd_i] = r_re;
  Sim[c * (BSZ * DIMC) + bd_i] = r_im;
}

__global__ __launch_bounds__(256) void scan_phase2(const float* __restrict__ phazor,
                                                   const float* __restrict__ Sre,
                                                   const float* __restrict__ Sim,
                                                   float* __restrict__ Cre,
                                                   float* __restrict__ Cim) {
  const int bd = blockIdx.x * 256 + threadIdx.x;  // 0..4095
  const int d = bd & (DIMC - 1);
  float p_re, p_im; get_p(phazor, d, p_re, p_im);
  float br = p_re, bi = p_im;                      // -> p^64
  #pragma unroll
  for (int i = 0; i < 6; ++i) { float t = br * br - bi * bi; bi = 2.f * br * bi; br = t; }
  float R_re = 0.f, R_im = 0.f;
  for (int c = 0; c < NCHUNK; ++c) {
    Cre[c * (BSZ * DIMC) + bd] = R_re;
    Cim[c * (BSZ * DIMC) + bd] = R_im;
    float sre = Sre[c * (BSZ * DIMC) + bd], sim = Sim[c * (BSZ * DIMC) + bd];
    float nr = br * R_re - bi * R_im + sre;
    float ni = br * R_im + bi * R_re + sim;
    R_re = nr; R_im = ni;
  }
}

__global__ __launch_bounds__(256) void scan_phase3(const float* __restrict__ x,
                                                   const float* __restrict__ mu,
                                                   const float* __restrict__ rstd,
                                                   const float* __restrict__ g,
                                                   const float* __restrict__ bb,
                                                   const float* __restrict__ phazor,
                                                   const float* __restrict__ phazor_init,
                                                   const float* __restrict__ last_re,
                                                   const float* __restrict__ last_im,
                                                   const float* __restrict__ Cre,
                                                   const float* __restrict__ Cim,
                                                   float* __restrict__ x2) {
  const int d = blockIdx.x * 256 + threadIdx.x;
  const int c = blockIdx.y;
  const int b = blockIdx.z;
  float p_re, p_im; get_p(phazor, d, p_re, p_im);
  const float pi_re = phazor_init[2 * d], pi_im = phazor_init[2 * d + 1];
  const float gd = g[d], bd_ = bb[d];
  const int bd_i = b * DIMC + d;
  float r_re = Cre[c * (BSZ * DIMC) + bd_i];
  float r_im = Cim[c * (BSZ * DIMC) + bd_i];
  float br = p_re, bi = p_im;
  #pragma unroll
  for (int i = 0; i < 6; ++i) { float t = br * br - bi * bi; bi = 2.f * br * bi; br = t; }
  float er = 1.f, ei = 0.f;
  int e = c;
  while (e) {
    if (e & 1) { float t = er * br - ei * bi; ei = er * bi + ei * br; er = t; }
    float t2 = br * br - bi * bi; bi = 2.f * br * bi; br = t2;
    e >>= 1;
  }
  const float lre = last_re[bd_i], lim = last_im[bd_i];
  float q_re = lre * er - lim * ei;
  float q_im = lre * ei + lim * er;
  const int t0 = c * CHUNK;
  const float* xp  = x + ((size_t)(b * LSEQ + t0)) * DIMC + d;
  const float* mup = mu + b * LSEQ + t0;
  const float* rp  = rstd + b * LSEQ + t0;
  float* op = x2 + ((size_t)(b * LSEQ + t0)) * DIMC + d;
  #pragma unroll 4
  for (int s = 0; s < CHUNK; ++s) {
    float xv = xp[(size_t)s * DIMC];
    float hv = (xv - mup[s]) * rp[s] * gd + bd_;
    float nr = p_re * r_re - p_im * r_im + hv;
    float ni = p_re * r_im + p_im * r_re;
    r_re = nr; r_im = ni;
    float nq = p_re * q_re - p_im * q_im;
    q_im = p_re * q_im + p_im * q_re;
    q_re = nq;
    op[(size_t)s * DIMC] = pi_re * r_re - pi_im * r_im + q_re + xv;
  }
}

// ---------------- pipelined MFMA GEMM (counted vmcnt, compiler-scheduled LDS waits) ----
// A [M][K] bf16, Bt [N][K] bf16. BM=256. BN=256: waves 2Mx4N (wave out 128x64);
// BN=128: waves 4Mx2N (wave out 64x64, balanced A/B reads).
// K-tile 64 split in kk halves of 32. LDS blocks [rows][32] with 16B-group XOR
// swizzle c' = c ^ ((row>>1)&3) (pre-swizzled global source + swizzled read).
// 4 phases per K-tile; stage one sub-block per phase; VMCNT(4|3) twice per tile.
// No forced lgkmcnt drain: compiler inserts fine-grained waits (m97 finding).
// Epilogue: C staged through LDS (swizzled) -> fully coalesced global stores.
// EPI 0: out = bf16(silu(acc+bias))   EPI 1: out = f32(acc+bias+resid)
template<int BN, int EPI>
__global__ __launch_bounds__(512, 2) void gemm8(const unsigned short* __restrict__ A,
                                                const unsigned short* __restrict__ Bt,
                                                const float* __restrict__ bias,
                                                const float* __restrict__ resid,
                                                void* __restrict__ outp,
                                                int M, int N, int K) {
  constexpr int AUS = 256 * 32;          // ushorts per A kk-block (16 KB)
  constexpr int BUS = BN * 32;           // ushorts per B kk-block
  constexpr int BUFUS = 2 * AUS + 2 * BUS;
  constexpr int MI = (BN == 256) ? 8 : 4;
  constexpr int LDSUS = (2 * BUFUS > 65536) ? 2 * BUFUS : 65536;
  __shared__ __align__(16) unsigned short lds[LDSUS];

  const int tid  = threadIdx.x;
  const int lane = tid & 63;
  const int wave = tid >> 6;
  const int wm = (BN == 256) ? (wave & 1) * 128 : (wave >> 1) * 64;
  const int wn = (BN == 256) ? (wave >> 1) * 64  : (wave & 1) * 64;
  const int r15 = lane & 15;
  const int cus = ((lane >> 4) ^ ((r15 >> 1) & 3)) * 8;  // swizzled col (ushorts)

  int bid = blockIdx.x;                   // XCD-aware swizzle (grid % 8 == 0)
  const int cpx = gridDim.x >> 3;
  bid = (bid & 7) * cpx + (bid >> 3);
  const int ntn = N / BN;
  const int tm = (bid / ntn) * 256;
  const int tn = (bid % ntn) * BN;
  const int NT = K >> 6;

  f32x4 acc[MI][4];
  #pragma unroll
  for (int i = 0; i < MI; ++i)
    #pragma unroll
    for (int j = 0; j < 4; ++j) acc[i][j] = (f32x4){0.f, 0.f, 0.f, 0.f};

  auto stageA = [&](int buf, int kk, int k0) {
    unsigned short* blk = lds + buf * BUFUS + kk * AUS;
    const unsigned short* g = A + (size_t)tm * K + k0 + kk * 32;
    #pragma unroll
    for (int r = 0; r < 2; ++r) {
      const int s = r * 512 + tid;
      const int row = s >> 2;
      const int cg = (s & 3) ^ ((s >> 3) & 3);   // source pre-swizzle
      async16(g + (size_t)row * K + cg * 8, blk + (size_t)s * 8);
    }
  };
  auto stageB = [&](int buf, int kk, int k0) {
    unsigned short* blk = lds + buf * BUFUS + 2 * AUS + kk * BUS;
    const unsigned short* g = Bt + (size_t)tn * K + k0 + kk * 32;
    #pragma unroll
    for (int r = 0; r < BN / 128; ++r) {
      const int s = r * 512 + tid;
      const int row = s >> 2;
      const int cg = (s & 3) ^ ((s >> 3) & 3);
      async16(g + (size_t)row * K + cg * 8, blk + (size_t)s * 8);
    }
  };
  auto rdA = [&](int buf, int kk, int mi) -> bf16x8 {
    return *(const bf16x8*)(lds + buf * BUFUS + kk * AUS + (wm + mi * 16 + r15) * 32 + cus);
  };
  auto rdB = [&](int buf, int kk, int ni) -> bf16x8 {
    return *(const bf16x8*)(lds + buf * BUFUS + 2 * AUS + kk * BUS + (wn + ni * 16 + r15) * 32 + cus);
  };

  bf16x8 af[MI], bq0, bq1, bq2, bq3;

  // prologue: tile 0 fully staged; counted vmcnt leaves kk1 loads in flight
  stageA(0, 0, 0); stageB(0, 0, 0); stageA(0, 1, 0); stageB(0, 1, 0);
  if constexpr (BN == 256) VMCNT(4); else VMCNT(3);
  bar();

  for (int t = 0; t < NT - 1; ++t) {
    const int buf = t & 1, nb = buf ^ 1, kn = (t + 1) << 6;
    // P0: kk0, ni 0-1
    #pragma unroll
    for (int mi = 0; mi < MI; ++mi) af[mi] = rdA(buf, 0, mi);
    bq0 = rdB(buf, 0, 0); bq1 = rdB(buf, 0, 1);
    stageA(nb, 0, kn);
    bar();
    __builtin_amdgcn_s_setprio(1);
    #pragma unroll
    for (int mi = 0; mi < MI; ++mi) {
      acc[mi][0] = MFMA_BF16(af[mi], bq0, acc[mi][0], 0, 0, 0);
      acc[mi][1] = MFMA_BF16(af[mi], bq1, acc[mi][1], 0, 0, 0);
    }
    __builtin_amdgcn_s_setprio(0);
    bar();
    // P1: kk0, ni 2-3
    bq2 = rdB(buf, 0, 2); bq3 = rdB(buf, 0, 3);
    stageB(nb, 0, kn);
    bar();
    __builtin_amdgcn_s_setprio(1);
    #pragma unroll
    for (int mi = 0; mi < MI; ++mi) {
      acc[mi][2] = MFMA_BF16(af[mi], bq2, acc[mi][2], 0, 0, 0);
      acc[mi][3] = MFMA_BF16(af[mi], bq3, acc[mi][3], 0, 0, 0);
    }
    __builtin_amdgcn_s_setprio(0);
    if constexpr (BN == 256) VMCNT(4); else VMCNT(3);   // kk1(t) landed
    bar();
    // P2: kk1, ni 0-1
    #pragma unroll
    for (int mi = 0; mi < MI; ++mi) af[mi] = rdA(buf, 1, mi);
    bq0 = rdB(buf, 1, 0); bq1 = rdB(buf, 1, 1);
    stageA(nb, 1, kn);
    bar();
    __builtin_amdgcn_s_setprio(1);
    #pragma unroll
    for (int mi = 0; mi < MI; ++mi) {
      acc[mi][0] = MFMA_BF16(af[mi], bq0, acc[mi][0], 0, 0, 0);
      acc[mi][1] = MFMA_BF16(af[mi], bq1, acc[mi][1], 0, 0, 0);
    }
    __builtin_amdgcn_s_setprio(0);
    bar();
    // P3: kk1, ni 2-3
    bq2 = rdB(buf, 1, 2); bq3 = rdB(buf, 1, 3);
    stageB(nb, 1, kn);
    bar();
    __builtin_amdgcn_s_setprio(1);
    #pragma unroll
    for (int mi = 0; mi < MI; ++mi) {
      acc[mi][2] = MFMA_BF16(af[mi], bq2, acc[mi][2], 0, 0, 0);
      acc[mi][3] = MFMA_BF16(af[mi], bq3, acc[mi][3], 0, 0, 0);
    }
    __builtin_amdgcn_s_setprio(0);
    if constexpr (BN == 256) VMCNT(4); else VMCNT(3);   // kk0(t+1) landed
    bar();
  }

  // final tile (no staging)
  {
    const int buf = (NT - 1) & 1;
    #pragma unroll
    for (int mi = 0; mi < MI; ++mi) af[mi] = rdA(buf, 0, mi);
    bq0 = rdB(buf, 0, 0); bq1 = rdB(buf, 0, 1);
    bar();
    #pragma unroll
    for (int mi = 0; mi < MI; ++mi) {
      acc[mi][0] = MFMA_BF16(af[mi], bq0, acc[mi][0], 0, 0, 0);
      acc[mi][1] = MFMA_BF16(af[mi], bq1, acc[mi][1], 0, 0, 0);
    }
    bar();
    bq2 = rdB(buf, 0, 2); bq3 = rdB(buf, 0, 3);
    #pragma unroll
    for (int mi = 0; mi < MI; ++mi) {
      acc[mi][2] = MFMA_BF16(af[mi], bq2, acc[mi][2], 0, 0, 0);
      acc[mi][3] = MFMA_BF16(af[mi], bq3, acc[mi][3], 0, 0, 0);
    }
    VMCNT(0);      // kk1 of final tile
    bar();
    #pragma unroll
    for (int mi = 0; mi < MI; ++mi) af[mi] = rdA(buf, 1, mi);
    bq0 = rdB(buf, 1, 0); bq1 = rdB(buf, 1, 1);
    bar();
    #pragma unroll
    for (int mi = 0; mi < MI; ++mi) {
      acc[mi][0] = MFMA_BF16(af[mi], bq0, acc[mi][0], 0, 0, 0);
      acc[mi][1] = MFMA_BF16(af[mi], bq1, acc[mi][1], 0, 0, 0);
    }
    bar();
    bq2 = rdB(buf, 1, 2); bq3 = rdB(buf, 1, 3);
    #pragma unroll
    for (int mi = 0; mi < MI; ++mi) {
      acc[mi][2] = MFMA_BF16(af[mi], bq2, acc[mi][2], 0, 0, 0);
      acc[mi][3] = MFMA_BF16(af[mi], bq3, acc[mi][3], 0, 0, 0);
    }
  }

  // ---- epilogue: stage C through LDS, then coalesced stores ----
  // C/D layout: col = lane&15, row = (lane>>4)*4 + j  [HW-verified]
  const int rg = (lane >> 4) * 4;
  float bias_r[4];
  #pragma unroll
  for (int ni = 0; ni < 4; ++ni) bias_r[ni] = bias[tn + wn + ni * 16 + r15];

  bar();   // all waves done with A/B LDS reads before overwrite
  if constexpr (EPI == 0) {
    unsigned short* C = lds;   // 256 x 256 bf16, col-swizzled per row
    #pragma unroll
    for (int mi = 0; mi < MI; ++mi)
      #pragma unroll
      for (int ni = 0; ni < 4; ++ni) {
        const int c0 = wn + ni * 16 + r15;
        #pragma unroll
        for (int j = 0; j < 4; ++j) {
          const int r = wm + mi * 16 + rg + j;
          const int key = (((r & 3) ^ ((r >> 2) & 3)) << 4);
          float v = acc[mi][ni][j] + bias_r[ni];
          v = v / (1.f + __expf(-v));
          C[r * 256 + (c0 ^ key)] = f2bf(v);
        }
      }
    bar();
    #pragma unroll
    for (int i = 0; i < 16; ++i) {
      const int off = i * 4096 + tid * 8;
      const int r = off >> 8;
      const int pc = off & 255;
      const int key = (((r & 3) ^ ((r >> 2) & 3)) << 4);
      bf16x8 v = *(const bf16x8*)(C + off);
      *(bf16x8*)((unsigned short*)outp + (size_t)(tm + r) * N + tn + (pc ^ key)) = v;
    }
  } else {
    float* C = (float*)lds;    // 256 x 128 f32, col-swizzled per row
    #pragma unroll
    for (int mi = 0; mi < MI; ++mi)
      #pragma unroll
      for (int ni = 0; ni < 4; ++ni) {
        const int c0 = wn + ni * 16 + r15;
        #pragma unroll
        for (int j = 0; j < 4; ++j) {
          const int r = wm + mi * 16 + rg + j;
          const int key = (((r & 3) ^ ((r >> 2) & 3)) << 4);
          C[r * 128 + (c0 ^ key)] = acc[mi][ni][j] + bias_r[ni];
        }
      }
    bar();
    #pragma unroll
    for (int i = 0; i < 16; ++i) {
      const int off = i * 2048 + tid * 4;
      const int r = off >> 7;
      const int pc = off & 127;
      const int key = (((r & 3) ^ ((r >> 2) & 3)) << 4);
      f32x4 v = *(const f32x4*)(C + off);
      const size_t gaddr = (size_t)(tm + r) * N + tn + (pc ^ key);
      f32x4 rv = *(const f32x4*)(resid + gaddr);
      v += rv;
      *(f32x4*)((float*)outp + gaddr) = v;
    }
  }
}

// ---------------- launch ----------------
extern "C" void kernel_launch(void* const* d_in, const int* in_sizes, int n_in,
                              void* d_out, int out_size, void* d_ws, size_t ws_size,
                              hipStream_t stream) {
  const float* x           = (const float*)d_in[0];
  const float* ln_g        = (const float*)d_in[1];
  const float* ln_b        = (const float*)d_in[2];
  const float* phazor      = (const float*)d_in[3];
  const float* phazor_init = (const float*)d_in[4];
  const float* w1          = (const float*)d_in[5];
  const float* b1          = (const float*)d_in[6];
  const float* w2          = (const float*)d_in[7];
  const float* b2          = (const float*)d_in[8];
  const float* last_re     = (const float*)d_in[9];
  const float* last_im     = (const float*)d_in[10];
  float* out = (float*)d_out;
  char* ws = (char*)d_ws;
  const size_t MB = 1ull << 20;

  float* x2  = (float*)(ws);                         // 32 MB
  float* mu1 = (float*)(ws + 32 * MB);               // 32 KB
  float* rs1 = (float*)(ws + 32 * MB + 64 * 1024);
  float* Sre = (float*)(ws + 32 * MB + 256 * 1024);  // 512 KB each
  float* Sim = (float*)(ws + 32 * MB + 768 * 1024);
  float* Cre = (float*)(ws + 32 * MB + 1280 * 1024);
  float* Cim = (float*)(ws + 32 * MB + 1792 * 1024);
  unsigned short* h2  = (unsigned short*)(ws + 35 * MB);   // 16 MB
  unsigned short* hid = (unsigned short*)(ws + 51 * MB);   // 64 MB
  unsigned short* w1t = (unsigned short*)(ws + 115 * MB);  // 8 MB
  unsigned short* w2t = (unsigned short*)(ws + 123 * MB);  // 8 MB

  transpose_bf16<<<dim3(DFFC / 32, DIMC / 32), dim3(32, 8), 0, stream>>>(w1, w1t, DIMC, DFFC);
  transpose_bf16<<<dim3(DIMC / 32, DFFC / 32), dim3(32, 8), 0, stream>>>(w2, w2t, DFFC, DIMC);

  ln_stats<<<NTOK, 256, 0, stream>>>(x, mu1, rs1);
  scan_phase1<<<dim3(DIMC / 256, NCHUNK, BSZ), 256, 0, stream>>>(x, mu1, rs1, ln_g, ln_b, phazor, Sre, Sim);
  scan_phase2<<<(BSZ * DIMC) / 256, 256, 0, stream>>>(phazor, Sre, Sim, Cre, Cim);
  scan_phase3<<<dim3(DIMC / 256, NCHUNK, BSZ), 256, 0, stream>>>(x, mu1, rs1, ln_g, ln_b, phazor,
                                                                 phazor_init, last_re, last_im,
                                                                 Cre, Cim, x2);
  ln_fused_bf16<<<NTOK, 256, 0, stream>>>(x2, ln_g, ln_b, h2);

  gemm8<256, 0><<<(NTOK / 256) * (DFFC / 256), 512, 0, stream>>>(h2, w1t, b1, nullptr, hid,
                                                                 NTOK, DFFC, DIMC);
  gemm8<128, 1><<<(NTOK / 256) * (DIMC / 128), 512, 0, stream>>>(hid, w2t, b2, x2, out,
                                                                 NTOK, DIMC, DFFC);
}

// Round 4
// 325.391 us; speedup vs baseline: 1.1644x; 1.0114x over previous
//
#include <hip/hip_runtime.h>
#include <stdint.h>
#include <stddef.h>

#define DIMC 1024
#define LSEQ 2048
#define BSZ  4
#define DFFC 4096
#define NTOK (BSZ*LSEQ)   // 8192 tokens
#define NCHUNK 32
#define CHUNK 64          // NCHUNK*CHUNK == LSEQ

typedef __bf16 bf16x8 __attribute__((ext_vector_type(8)));
typedef float  f32x4  __attribute__((ext_vector_type(4)));

__device__ __forceinline__ unsigned short f2bf(float f) {
  unsigned int u = __float_as_uint(f);
  u += 0x7fffu + ((u >> 16) & 1u);      // RNE
  return (unsigned short)(u >> 16);
}

__device__ __forceinline__ void async16(const void* g, void* l) {
  __builtin_amdgcn_global_load_lds(
      (const __attribute__((address_space(1))) unsigned int*)(uintptr_t)g,
      (__attribute__((address_space(3))) unsigned int*)(uintptr_t)l,
      16, 0, 0);
}

__device__ __forceinline__ void bar() {
  asm volatile("" ::: "memory");
  __builtin_amdgcn_s_barrier();
  asm volatile("" ::: "memory");
}
#define LGKM0 do { asm volatile("s_waitcnt lgkmcnt(0)" ::: "memory"); \
                   __builtin_amdgcn_sched_barrier(0); } while (0)
#define VMCNT(n) asm volatile("s_waitcnt vmcnt(" #n ")" ::: "memory")
template <int N> __device__ __forceinline__ void vmwait() {
  if constexpr (N == 0) VMCNT(0);
  else if constexpr (N == 3) VMCNT(3);
  else if constexpr (N == 4) VMCNT(4);
  else if constexpr (N == 6) VMCNT(6);
  else if constexpr (N == 8) VMCNT(8);
}
#define MFMA_BF16 __builtin_amdgcn_mfma_f32_16x16x32_bf16

// ---------------- LayerNorm stats: one block per token ----------------
__global__ __launch_bounds__(256) void ln_stats(const float* __restrict__ x,
                                                float* __restrict__ mu,
                                                float* __restrict__ rstd) {
  const int token = blockIdx.x;
  const float4* xp = (const float4*)(x + (size_t)token * DIMC);
  float4 v = xp[threadIdx.x];
  float s  = v.x + v.y + v.z + v.w;
  float s2 = v.x*v.x + v.y*v.y + v.z*v.z + v.w*v.w;
  #pragma unroll
  for (int o = 32; o; o >>= 1) { s += __shfl_down(s, o); s2 += __shfl_down(s2, o); }
  __shared__ float sh[8];
  const int lane = threadIdx.x & 63, w = threadIdx.x >> 6;
  if (lane == 0) { sh[w] = s; sh[4 + w] = s2; }
  __syncthreads();
  if (threadIdx.x == 0) {
    float ts  = sh[0] + sh[1] + sh[2] + sh[3];
    float ts2 = sh[4] + sh[5] + sh[6] + sh[7];
    float m = ts * (1.f / DIMC);
    float var = ts2 * (1.f / DIMC) - m * m;
    mu[token] = m;
    rstd[token] = rsqrtf(var + 1e-5f);
  }
}

// ---------------- fused LN (stats + apply) -> bf16 ----------------
__global__ __launch_bounds__(256) void ln_fused_bf16(const float* __restrict__ x,
                                                     const float* __restrict__ g,
                                                     const float* __restrict__ bb,
                                                     unsigned short* __restrict__ out) {
  const int token = blockIdx.x;
  const float4* xp = (const float4*)(x + (size_t)token * DIMC);
  float4 v = xp[threadIdx.x];
  float s  = v.x + v.y + v.z + v.w;
  float s2 = v.x*v.x + v.y*v.y + v.z*v.z + v.w*v.w;
  #pragma unroll
  for (int o = 32; o; o >>= 1) { s += __shfl_down(s, o); s2 += __shfl_down(s2, o); }
  __shared__ float sh[10];
  const int lane = threadIdx.x & 63, w = threadIdx.x >> 6;
  if (lane == 0) { sh[w] = s; sh[4 + w] = s2; }
  __syncthreads();
  if (threadIdx.x == 0) {
    float ts  = sh[0] + sh[1] + sh[2] + sh[3];
    float ts2 = sh[4] + sh[5] + sh[6] + sh[7];
    float m = ts * (1.f / DIMC);
    float var = ts2 * (1.f / DIMC) - m * m;
    sh[8] = m;
    sh[9] = rsqrtf(var + 1e-5f);
  }
  __syncthreads();
  const float m = sh[8], r = sh[9];
  float4 gv = ((const float4*)g)[threadIdx.x];
  float4 bv = ((const float4*)bb)[threadIdx.x];
  ushort4 o;
  o.x = f2bf((v.x - m) * r * gv.x + bv.x);
  o.y = f2bf((v.y - m) * r * gv.y + bv.y);
  o.z = f2bf((v.z - m) * r * gv.z + bv.z);
  o.w = f2bf((v.w - m) * r * gv.w + bv.w);
  ((ushort4*)(out + (size_t)token * DIMC))[threadIdx.x] = o;
}

// ---------------- transpose fp32 [K][N] -> bf16 [N][K] ----------------
__global__ __launch_bounds__(256) void transpose_bf16(const float* __restrict__ w,
                                                      unsigned short* __restrict__ wt,
                                                      int K, int N) {
  __shared__ float tile[32][33];
  const int n0 = blockIdx.x * 32, k0 = blockIdx.y * 32;
  const int tx = threadIdx.x, ty = threadIdx.y;   // 32 x 8
  #pragma unroll
  for (int i = 0; i < 32; i += 8)
    tile[ty + i][tx] = w[(size_t)(k0 + ty + i) * N + n0 + tx];
  __syncthreads();
  #pragma unroll
  for (int i = 0; i < 32; i += 8)
    wt[(size_t)(n0 + ty + i) * K + k0 + tx] = f2bf(tile[tx][ty + i]);
}

// ---------------- spiral scan (3-phase chunked) ----------------
__device__ __forceinline__ void get_p(const float* __restrict__ phazor, int d,
                                      float& p_re, float& p_im) {
  float pre = phazor[2 * d], pim = phazor[2 * d + 1];
  float a = sqrtf(pre * pre + pim * pim);
  float sc = expf(-a) / a;
  p_re = pre * sc;
  p_im = pim * sc;
}

__global__ __launch_bounds__(256) void scan_phase1(const float* __restrict__ x,
                                                   const float* __restrict__ mu,
                                                   const float* __restrict__ rstd,
                                                   const float* __restrict__ g,
                                                   const float* __restrict__ bb,
                                                   const float* __restrict__ phazor,
                                                   float* __restrict__ Sre,
                                                   float* __restrict__ Sim) {
  const int d = blockIdx.x * 256 + threadIdx.x;
  const int c = blockIdx.y;
  const int b = blockIdx.z;
  float p_re, p_im; get_p(phazor, d, p_re, p_im);
  const float gd = g[d], bd = bb[d];
  const int t0 = c * CHUNK;
  const float* xp  = x + ((size_t)(b * LSEQ + t0)) * DIMC + d;
  const float* mup = mu + b * LSEQ + t0;
  const float* rp  = rstd + b * LSEQ + t0;
  float r_re = 0.f, r_im = 0.f;
  #pragma unroll
  for (int s8 = 0; s8 < CHUNK; s8 += 8) {
    float xv[8];
    #pragma unroll
    for (int k = 0; k < 8; ++k) xv[k] = xp[(size_t)(s8 + k) * DIMC];
    #pragma unroll
    for (int k = 0; k < 8; ++k) {
      float hv = (xv[k] - mup[s8 + k]) * rp[s8 + k] * gd + bd;
      float nr = p_re * r_re - p_im * r_im + hv;
      float ni = p_re * r_im + p_im * r_re;
      r_re = nr; r_im = ni;
    }
  }
  const int bd_i = b * DIMC + d;
  Sre[c * (BSZ * DIMC) + bd_i] = r_re;
  Sim[c * (BSZ * DIMC) + bd_i] = r_im;
}

__global__ __launch_bounds__(256) void scan_phase2(const float* __restrict__ phazor,
                                                   const float* __restrict__ Sre,
                                                   const float* __restrict__ Sim,
                                                   float* __restrict__ Cre,
                                                   float* __restrict__ Cim) {
  const int bd = blockIdx.x * 256 + threadIdx.x;  // 0..4095
  const int d = bd & (DIMC - 1);
  float p_re, p_im; get_p(phazor, d, p_re, p_im);
  float br = p_re, bi = p_im;                      // -> p^64
  #pragma unroll
  for (int i = 0; i < 6; ++i) { float t = br * br - bi * bi; bi = 2.f * br * bi; br = t; }
  float sre[NCHUNK], sim[NCHUNK];
  #pragma unroll
  for (int c = 0; c < NCHUNK; ++c) {              // independent batched loads
    sre[c] = Sre[c * (BSZ * DIMC) + bd];
    sim[c] = Sim[c * (BSZ * DIMC) + bd];
  }
  float R_re = 0.f, R_im = 0.f;
  #pragma unroll
  for (int c = 0; c < NCHUNK; ++c) {
    Cre[c * (BSZ * DIMC) + bd] = R_re;
    Cim[c * (BSZ * DIMC) + bd] = R_im;
    float nr = br * R_re - bi * R_im + sre[c];
    float ni = br * R_im + bi * R_re + sim[c];
    R_re = nr; R_im = ni;
  }
}

__global__ __launch_bounds__(256) void scan_phase3(const float* __restrict__ x,
                                                   const float* __restrict__ mu,
                                                   const float* __restrict__ rstd,
                                                   const float* __restrict__ g,
                                                   const float* __restrict__ bb,
                                                   const float* __restrict__ phazor,
                                                   const float* __restrict__ phazor_init,
                                                   const float* __restrict__ last_re,
                                                   const float* __restrict__ last_im,
                                                   const float* __restrict__ Cre,
                                                   const float* __restrict__ Cim,
                                                   float* __restrict__ x2) {
  const int d = blockIdx.x * 256 + threadIdx.x;
  const int c = blockIdx.y;
  const int b = blockIdx.z;
  float p_re, p_im; get_p(phazor, d, p_re, p_im);
  const float pi_re = phazor_init[2 * d], pi_im = phazor_init[2 * d + 1];
  const float gd = g[d], bd_ = bb[d];
  const int bd_i = b * DIMC + d;
  float r_re = Cre[c * (BSZ * DIMC) + bd_i];
  float r_im = Cim[c * (BSZ * DIMC) + bd_i];
  float br = p_re, bi = p_im;
  #pragma unroll
  for (int i = 0; i < 6; ++i) { float t = br * br - bi * bi; bi = 2.f * br * bi; br = t; }
  float er = 1.f, ei = 0.f;
  int e = c;
  while (e) {
    if (e & 1) { float t = er * br - ei * bi; ei = er * bi + ei * br; er = t; }
    float t2 = br * br - bi * bi; bi = 2.f * br * bi; br = t2;
    e >>= 1;
  }
  const float lre = last_re[bd_i], lim = last_im[bd_i];
  float q_re = lre * er - lim * ei;
  float q_im = lre * ei + lim * er;
  const int t0 = c * CHUNK;
  const float* xp  = x + ((size_t)(b * LSEQ + t0)) * DIMC + d;
  const float* mup = mu + b * LSEQ + t0;
  const float* rp  = rstd + b * LSEQ + t0;
  float* op = x2 + ((size_t)(b * LSEQ + t0)) * DIMC + d;
  #pragma unroll
  for (int s8 = 0; s8 < CHUNK; s8 += 8) {
    float xv[8];
    #pragma unroll
    for (int k = 0; k < 8; ++k) xv[k] = xp[(size_t)(s8 + k) * DIMC];
    #pragma unroll
    for (int k = 0; k < 8; ++k) {
      float hv = (xv[k] - mup[s8 + k]) * rp[s8 + k] * gd + bd_;
      float nr = p_re * r_re - p_im * r_im + hv;
      float ni = p_re * r_im + p_im * r_re;
      r_re = nr; r_im = ni;
      float nq = p_re * q_re - p_im * q_im;
      q_im = p_re * q_im + p_im * q_re;
      q_re = nq;
      op[(size_t)(s8 + k) * DIMC] = pi_re * r_re - pi_im * r_im + q_re + xv[k];
    }
  }
}

// ---------------- m201-style 8-phase MFMA GEMM ----------------
// A [M][K] bf16, Bt [N][K] bf16. BM=256. 512 thr, 8 waves 2Mx4N.
// BN=256: wave out 128x64 (NI=4); BN=128: wave out 128x32 (NI=2).
// K-tile 64, kk halves of 32. Iteration = 2 K-tiles = 8 phases.
// Phase (kk, mh): 4 A ds_reads (+NI B at mh=0), 16|8 MFMA, 2|1.5 staged loads.
// Stage slots lead consumption by 5-6 phases; counted vmcnt at even-phase ends
// (before closing barrier -> barrier publishes cross-wave completion).
// LDS [buf][kk][row][32] with 16B-group XOR swizzle (source-preswizzled).
// EPI 0: bf16(silu(acc+bias)); EPI 1: f32(acc+bias+resid). Epilogue via LDS.
template<int BN, int EPI>
__global__ __launch_bounds__(512, 2) void gemm8(const unsigned short* __restrict__ A,
                                                const unsigned short* __restrict__ Bt,
                                                const float* __restrict__ bias,
                                                const float* __restrict__ resid,
                                                void* __restrict__ outp,
                                                int M, int N, int K) {
  constexpr int AUS = 256 * 32;          // ushorts per A kk-block (16 KB)
  constexpr int BUS = BN * 32;           // ushorts per B kk-block
  constexpr int BUFUS = 2 * AUS + 2 * BUS;
  constexpr int NI = (BN == 256) ? 4 : 2;
  constexpr int LDSUS = (2 * BUFUS > 65536) ? 2 * BUFUS : 65536;
  __shared__ __align__(16) unsigned short lds[LDSUS];

  const int tid  = threadIdx.x;
  const int lane = tid & 63;
  const int wave = tid >> 6;
  const int wm = (wave & 1) * 128;
  const int wn = (wave >> 1) * (BN / 4);
  const int r15 = lane & 15;
  const int cus = ((lane >> 4) ^ ((r15 >> 1) & 3)) * 8;  // swizzled col (ushorts)

  int bid = blockIdx.x;                   // XCD-aware swizzle (grid % 8 == 0)
  const int cpx = gridDim.x >> 3;
  bid = (bid & 7) * cpx + (bid >> 3);
  const int ntn = N / BN;
  const int tm = (bid / ntn) * 256;
  const int tn = (bid % ntn) * BN;
  const int NT = K >> 6;                  // even (16 or 64)

  f32x4 acc[8][NI];
  #pragma unroll
  for (int i = 0; i < 8; ++i)
    #pragma unroll
    for (int j = 0; j < NI; ++j) acc[i][j] = (f32x4){0.f, 0.f, 0.f, 0.f};

  auto stageA1 = [&](int buf, int kk, int k0, int half) {   // one gload_lds
    unsigned short* blk = lds + buf * BUFUS + kk * AUS;
    const unsigned short* g = A + (size_t)tm * K + k0 + kk * 32;
    const int s = half * 512 + tid;
    const int row = s >> 2;
    const int cg = (s & 3) ^ ((s >> 3) & 3);   // source pre-swizzle
    async16(g + (size_t)row * K + cg * 8, blk + (size_t)s * 8);
  };
  auto stageB1 = [&](int buf, int kk, int k0, int half) {
    unsigned short* blk = lds + buf * BUFUS + 2 * AUS + kk * BUS;
    const unsigned short* g = Bt + (size_t)tn * K + k0 + kk * 32;
    const int s = half * 512 + tid;
    const int row = s >> 2;
    const int cg = (s & 3) ^ ((s >> 3) & 3);
    async16(g + (size_t)row * K + cg * 8, blk + (size_t)s * 8);
  };
  auto stageBb = [&](int buf, int kk, int k0) {   // 2nd B half only when BN=256
    if constexpr (BN == 256) stageB1(buf, kk, k0, 1);
  };
  auto rdA = [&](int buf, int kk, int mi) -> bf16x8 {
    return *(const bf16x8*)(lds + buf * BUFUS + kk * AUS + (wm + mi * 16 + r15) * 32 + cus);
  };
  auto rdB = [&](int buf, int kk, int ni) -> bf16x8 {
    return *(const bf16x8*)(lds + buf * BUFUS + 2 * AUS + kk * BUS + (wn + ni * 16 + r15) * 32 + cus);
  };

  bf16x8 af[4], bq[NI];
  constexpr int VMS = (BN == 256) ? 8 : 6;       // steady-state counted wait
  constexpr int VMP = (BN == 256) ? 4 : 3;       // peel ph4-end wait

// PH: one phase. BREAD literal; WAIT statement runs after MFMA, before closing
// barrier (so the barrier publishes the landed loads chip-wide). Stages via
// __VA_ARGS__ (issued after this phase's ds_reads -> W-after-R safe: target
// region's reads completed 2 phases ago, sealed by that phase's barrier).
#define PH(buf, kk, mh, BREAD, WAIT, ...)                                       \
  {                                                                             \
    _Pragma("unroll")                                                           \
    for (int q = 0; q < 4; ++q) af[q] = rdA(buf, kk, (mh) * 4 + q);             \
    if (BREAD) {                                                                \
      _Pragma("unroll")                                                         \
      for (int n = 0; n < NI; ++n) bq[n] = rdB(buf, kk, n);                     \
    }                                                                           \
    __VA_ARGS__;                                                                \
    bar(); LGKM0;                                                               \
    __builtin_amdgcn_s_setprio(1);                                              \
    _Pragma("unroll")                                                           \
    for (int q = 0; q < 4; ++q)                                                 \
      _Pragma("unroll")                                                         \
      for (int n = 0; n < NI; ++n)                                              \
        acc[(mh) * 4 + q][n] = MFMA_BF16(af[q], bq[n], acc[(mh) * 4 + q][n], 0, 0, 0); \
    __builtin_amdgcn_s_setprio(0);                                              \
    WAIT;                                                                       \
    bar();                                                                      \
  }

  // prologue: t0 (buf0) fully + t1.kk0 (buf1); t1.kk1 staged in iter0 ph1-2
  stageA1(0, 0, 0, 0); stageA1(0, 0, 0, 1); stageB1(0, 0, 0, 0); stageBb(0, 0, 0);
  stageA1(0, 1, 0, 0); stageA1(0, 1, 0, 1); stageB1(0, 1, 0, 0); stageBb(0, 1, 0);
  stageA1(1, 0, 64, 0); stageA1(1, 0, 64, 1); stageB1(1, 0, 64, 0); stageBb(1, 0, 64);
  vmwait<VMS>();
  bar();

  for (int i = 0; i < NT / 2 - 1; ++i) {
    const int kb = (2 * i + 1) * 64, kc = kb + 64, kd = kc + 64;
    PH(0, 0, 0, 1, ((void)0),    stageA1(1, 1, kb, 0); stageA1(1, 1, kb, 1))
    PH(0, 0, 1, 0, vmwait<VMS>(), stageB1(1, 1, kb, 0); stageBb(1, 1, kb))
    PH(0, 1, 0, 1, ((void)0),    stageA1(0, 0, kc, 0); stageA1(0, 0, kc, 1))
    PH(0, 1, 1, 0, vmwait<VMS>(), stageB1(0, 0, kc, 0); stageBb(0, 0, kc))
    PH(1, 0, 0, 1, ((void)0),    stageA1(0, 1, kc, 0); stageA1(0, 1, kc, 1))
    PH(1, 0, 1, 0, vmwait<VMS>(), stageB1(0, 1, kc, 0); stageBb(0, 1, kc))
    PH(1, 1, 0, 1, ((void)0),    stageA1(1, 0, kd, 0); stageA1(1, 0, kd, 1))
    PH(1, 1, 1, 0, vmwait<VMS>(), stageB1(1, 0, kd, 0); stageBb(1, 0, kd))
  }

  { // peeled last iteration: only t(NT-1).kk1 still needs staging
    const int kb = (NT - 1) * 64;
    PH(0, 0, 0, 1, ((void)0),    stageA1(1, 1, kb, 0); stageA1(1, 1, kb, 1))
    PH(0, 0, 1, 0, vmwait<VMS>(), stageB1(1, 1, kb, 0); stageBb(1, 1, kb))
    PH(0, 1, 0, 1, ((void)0),    ((void)0))
    PH(0, 1, 1, 0, vmwait<VMP>(), ((void)0))
    PH(1, 0, 0, 1, ((void)0),    ((void)0))
    PH(1, 0, 1, 0, vmwait<0>(),  ((void)0))
    PH(1, 1, 0, 1, ((void)0),    ((void)0))
    PH(1, 1, 1, 0, ((void)0),    ((void)0))
  }
#undef PH

  // ---- epilogue: stage C through LDS, then coalesced stores ----
  // C/D layout: col = lane&15, row = (lane>>4)*4 + j  [HW-verified]
  const int rg = (lane >> 4) * 4;
  float bias_r[NI];
  #pragma unroll
  for (int ni = 0; ni < NI; ++ni) bias_r[ni] = bias[tn + wn + ni * 16 + r15];

  bar();   // all waves past final phase (already sealed, belt-and-suspenders)
  if constexpr (EPI == 0) {
    unsigned short* C = lds;   // 256 x 256 bf16, col-swizzled per row
    #pragma unroll
    for (int mi = 0; mi < 8; ++mi)
      #pragma unroll
      for (int ni = 0; ni < NI; ++ni) {
        const int c0 = wn + ni * 16 + r15;
        #pragma unroll
        for (int j = 0; j < 4; ++j) {
          const int r = wm + mi * 16 + rg + j;
          const int key = (((r & 3) ^ ((r >> 2) & 3)) << 4);
          float v = acc[mi][ni][j] + bias_r[ni];
          v = v / (1.f + __expf(-v));
          C[r * 256 + (c0 ^ key)] = f2bf(v);
        }
      }
    bar();
    #pragma unroll
    for (int i = 0; i < 16; ++i) {
      const int off = i * 4096 + tid * 8;
      const int r = off >> 8;
      const int pc = off & 255;
      const int key = (((r & 3) ^ ((r >> 2) & 3)) << 4);
      bf16x8 v = *(const bf16x8*)(C + off);
      *(bf16x8*)((unsigned short*)outp + (size_t)(tm + r) * N + tn + (pc ^ key)) = v;
    }
  } else {
    float* C = (float*)lds;    // 256 x 128 f32, col-swizzled per row
    #pragma unroll
    for (int mi = 0; mi < 8; ++mi)
      #pragma unroll
      for (int ni = 0; ni < NI; ++ni) {
        const int c0 = wn + ni * 16 + r15;
        #pragma unroll
        for (int j = 0; j < 4; ++j) {
          const int r = wm + mi * 16 + rg + j;
          const int key = (((r & 3) ^ ((r >> 2) & 3)) << 4);
          C[r * 128 + (c0 ^ key)] = acc[mi][ni][j] + bias_r[ni];
        }
      }
    bar();
    #pragma unroll
    for (int i = 0; i < 16; ++i) {
      const int off = i * 2048 + tid * 4;
      const int r = off >> 7;
      const int pc = off & 127;
      const int key = (((r & 3) ^ ((r >> 2) & 3)) << 4);
      f32x4 v = *(const f32x4*)(C + off);
      const size_t gaddr = (size_t)(tm + r) * N + tn + (pc ^ key);
      f32x4 rv = *(const f32x4*)(resid + gaddr);
      v += rv;
      *(f32x4*)((float*)outp + gaddr) = v;
    }
  }
}

// ---------------- launch ----------------
extern "C" void kernel_launch(void* const* d_in, const int* in_sizes, int n_in,
                              void* d_out, int out_size, void* d_ws, size_t ws_size,
                              hipStream_t stream) {
  const float* x           = (const float*)d_in[0];
  const float* ln_g        = (const float*)d_in[1];
  const float* ln_b        = (const float*)d_in[2];
  const float* phazor      = (const float*)d_in[3];
  const float* phazor_init = (const float*)d_in[4];
  const float* w1          = (const float*)d_in[5];
  const float* b1          = (const float*)d_in[6];
  const float* w2          = (const float*)d_in[7];
  const float* b2          = (const float*)d_in[8];
  const float* last_re     = (const float*)d_in[9];
  const float* last_im     = (const float*)d_in[10];
  float* out = (float*)d_out;
  char* ws = (char*)d_ws;
  const size_t MB = 1ull << 20;

  float* x2  = (float*)(ws);                         // 32 MB
  float* mu1 = (float*)(ws + 32 * MB);               // 32 KB
  float* rs1 = (float*)(ws + 32 * MB + 64 * 1024);
  float* Sre = (float*)(ws + 32 * MB + 256 * 1024);  // 512 KB each
  float* Sim = (float*)(ws + 32 * MB + 768 * 1024);
  float* Cre = (float*)(ws + 32 * MB + 1280 * 1024);
  float* Cim = (float*)(ws + 32 * MB + 1792 * 1024);
  unsigned short* h2  = (unsigned short*)(ws + 35 * MB);   // 16 MB
  unsigned short* hid = (unsigned short*)(ws + 51 * MB);   // 64 MB
  unsigned short* w1t = (unsigned short*)(ws + 115 * MB);  // 8 MB
  unsigned short* w2t = (unsigned short*)(ws + 123 * MB);  // 8 MB

  transpose_bf16<<<dim3(DFFC / 32, DIMC / 32), dim3(32, 8), 0, stream>>>(w1, w1t, DIMC, DFFC);
  transpose_bf16<<<dim3(DIMC / 32, DFFC / 32), dim3(32, 8), 0, stream>>>(w2, w2t, DFFC, DIMC);

  ln_stats<<<NTOK, 256, 0, stream>>>(x, mu1, rs1);
  scan_phase1<<<dim3(DIMC / 256, NCHUNK, BSZ), 256, 0, stream>>>(x, mu1, rs1, ln_g, ln_b, phazor, Sre, Sim);
  scan_phase2<<<(BSZ * DIMC) / 256, 256, 0, stream>>>(phazor, Sre, Sim, Cre, Cim);
  scan_phase3<<<dim3(DIMC / 256, NCHUNK, BSZ), 256, 0, stream>>>(x, mu1, rs1, ln_g, ln_b, phazor,
                                                                 phazor_init, last_re, last_im,
                                                                 Cre, Cim, x2);
  ln_fused_bf16<<<NTOK, 256, 0, stream>>>(x2, ln_g, ln_b, h2);

  gemm8<256, 0><<<(NTOK / 256) * (DFFC / 256), 512, 0, stream>>>(h2, w1t, b1, nullptr, hid,
                                                                 NTOK, DFFC, DIMC);
  gemm8<128, 1><<<(NTOK / 256) * (DIMC / 128), 512, 0, stream>>>(hid, w2t, b2, x2, out,
                                                                 NTOK, DIMC, DFFC);
}